// Round 5
// baseline (104.399 us; speedup 1.0000x reference)
//
#include <hip/hip_runtime.h>
#include <hip/hip_bf16.h>

// Problem: chamfer(gt[4,8192,3], rec[4,8192,3]) + mean KL over mean/logvar [4,256,64].
// Strategy: never materialize the 268M-entry distance tensor. Brute-force
// nearest-neighbor both directions, register-blocked; all data L2-resident so
// the kernel is VALU-bound (~24us theoretical floor at 3.5 VALU ops/pair/dir).
//
// min_y ||x-y||^2 = x^2 + min_y (y^2 - 2 x.y); precompute x' = -2x so each
// pair costs 3 chained FMAs; process 2 y per iteration so one v_min3_f32
// replaces two v_min_f32. P=4 x-points per thread -> 28 VALU per 2 LDS
// broadcast reads, keeping the single LDS pipe well under capacity.

#define NPTS   8192
#define BATCH  4
#define CHUNK  512      // y-points per block pass
#define NCHUNK 16       // 8192 / 512
#define XTILE  1024     // x-points per block (4 per thread)
#define NTILE  8        // 8192 / 1024

// Order-preserving map float -> uint (works for negatives too).
__device__ __forceinline__ unsigned flip_f(float f) {
  unsigned u = __float_as_uint(f);
  unsigned mask = (unsigned)(-(int)(u >> 31)) | 0x80000000u;
  return u ^ mask;
}
__device__ __forceinline__ float unflip_f(unsigned k) {
  unsigned mask = ((k >> 31) - 1u) | 0x80000000u;
  return __uint_as_float(k ^ mask);
}

// Pack points as {x,y,z,||p||^2}, init min arrays to +inf-key, zero the output
// (d_out/d_ws are poisoned 0xAA before every timed launch).
__global__ void init_kernel(const float* __restrict__ gt, const float* __restrict__ rec,
                            float4* __restrict__ gt4, float4* __restrict__ rec4,
                            unsigned* __restrict__ d1min, unsigned* __restrict__ d2min,
                            float* __restrict__ out) {
  int t = blockIdx.x * blockDim.x + threadIdx.x;  // 0..32767
  float a0 = gt[3*t], a1 = gt[3*t+1], a2 = gt[3*t+2];
  gt4[t] = make_float4(a0, a1, a2, fmaf(a0, a0, fmaf(a1, a1, a2*a2)));
  float b0 = rec[3*t], b1 = rec[3*t+1], b2 = rec[3*t+2];
  rec4[t] = make_float4(b0, b1, b2, fmaf(b0, b0, fmaf(b1, b1, b2*b2)));
  d1min[t] = 0xFFFFFFFFu;  // max key == +inf identity for min
  d2min[t] = 0xFFFFFFFFu;
  if (t == 0) out[0] = 0.0f;
}

// grid.x = 8 tiles * 4 batches * 16 chunks * 2 directions = 1024 blocks
// (= 4 blocks/CU, 16 waves/CU, 32 KiB LDS/CU).
// Inner loop per 2y: 2 uniform-address ds_read_b128 (broadcast, conflict-free)
// + per-4x {24 fma, 4 min3}. Cross-chunk reduction via order-preserving
// atomicMin on uint keys.
__global__ __launch_bounds__(256, 4) void chamfer_kernel(
    const float4* __restrict__ gt4, const float4* __restrict__ rec4,
    unsigned* __restrict__ d1min, unsigned* __restrict__ d2min) {
  __shared__ float4 ytile[CHUNK];   // 8 KiB

  int bx    = blockIdx.x;
  int dir   = bx & 1;
  int chunk = (bx >> 1) & (NCHUNK - 1);
  int b     = (bx >> 5) & (BATCH - 1);
  int tile  = bx >> 7;                      // 0..7
  const float4* xs = dir ? rec4 : gt4;
  const float4* ys = dir ? gt4 : rec4;
  unsigned* dmin   = dir ? d2min : d1min;

  // stage y-chunk to LDS (2 float4 per thread); x-loads overlap the staging
  const float4* yp = ys + b * NPTS + chunk * CHUNK;
  ytile[threadIdx.x]       = yp[threadIdx.x];
  ytile[threadIdx.x + 256] = yp[threadIdx.x + 256];

  int i0 = tile * XTILE + threadIdx.x;
  const float4* xp = xs + b * NPTS;
  float4 x0 = xp[i0];
  float4 x1 = xp[i0 + 256];
  float4 x2 = xp[i0 + 512];
  float4 x3 = xp[i0 + 768];
  // x' = -2x so e = fma(x'x,yx, fma(x'y,yy, fma(x'z,yz, y2)))
  float a0x = -2.0f*x0.x, a0y = -2.0f*x0.y, a0z = -2.0f*x0.z;
  float a1x = -2.0f*x1.x, a1y = -2.0f*x1.y, a1z = -2.0f*x1.z;
  float a2x = -2.0f*x2.x, a2y = -2.0f*x2.y, a2z = -2.0f*x2.z;
  float a3x = -2.0f*x3.x, a3y = -2.0f*x3.y, a3z = -2.0f*x3.z;

  __syncthreads();

  const float INF = 3.402823466e38f;
  float m0 = INF, m1 = INF, m2 = INF, m3 = INF;
#pragma unroll 4
  for (int m = 0; m < CHUNK; m += 2) {
    float4 y0 = ytile[m];
    float4 y1 = ytile[m + 1];
    float e00 = fmaf(a0x, y0.x, fmaf(a0y, y0.y, fmaf(a0z, y0.z, y0.w)));
    float e01 = fmaf(a0x, y1.x, fmaf(a0y, y1.y, fmaf(a0z, y1.z, y1.w)));
    float e10 = fmaf(a1x, y0.x, fmaf(a1y, y0.y, fmaf(a1z, y0.z, y0.w)));
    float e11 = fmaf(a1x, y1.x, fmaf(a1y, y1.y, fmaf(a1z, y1.z, y1.w)));
    float e20 = fmaf(a2x, y0.x, fmaf(a2y, y0.y, fmaf(a2z, y0.z, y0.w)));
    float e21 = fmaf(a2x, y1.x, fmaf(a2y, y1.y, fmaf(a2z, y1.z, y1.w)));
    float e30 = fmaf(a3x, y0.x, fmaf(a3y, y0.y, fmaf(a3z, y0.z, y0.w)));
    float e31 = fmaf(a3x, y1.x, fmaf(a3y, y1.y, fmaf(a3z, y1.z, y1.w)));
    m0 = fminf(fminf(m0, e00), e01);   // -> v_min3_f32
    m1 = fminf(fminf(m1, e10), e11);
    m2 = fminf(fminf(m2, e20), e21);
    m3 = fminf(fminf(m3, e30), e31);
  }
  atomicMin(&dmin[b * NPTS + i0],        flip_f(m0));
  atomicMin(&dmin[b * NPTS + i0 + 256],  flip_f(m1));
  atomicMin(&dmin[b * NPTS + i0 + 512],  flip_f(m2));
  atomicMin(&dmin[b * NPTS + i0 + 768],  flip_f(m3));
}

// 64 blocks x 256: sum (x^2 + min_e) both directions, plus the KL term.
__global__ void finalize_kernel(const float4* __restrict__ gt4, const float4* __restrict__ rec4,
                                const unsigned* __restrict__ d1min, const unsigned* __restrict__ d2min,
                                const float* __restrict__ mean, const float* __restrict__ logvar,
                                float* __restrict__ out) {
  int t = blockIdx.x * blockDim.x + threadIdx.x;  // 0..16383
  float s = 0.0f;
  for (int j = t; j < BATCH * NPTS; j += 16384) {
    s += gt4[j].w  + unflip_f(d1min[j]);
    s += rec4[j].w + unflip_f(d2min[j]);
  }
  s *= (1.0f / (BATCH * NPTS));
  float k = 0.0f;
  for (int j = t; j < BATCH * 256 * 64; j += 16384) {
    float m = mean[j], lv = logvar[j];
    k += fmaf(m, m, expf(lv) - 1.0f - lv);
  }
  s += k * (0.5f / BATCH);

  // wave reduce then cross-wave via LDS
  for (int off = 32; off > 0; off >>= 1) s += __shfl_down(s, off);
  __shared__ float wsum[4];
  int lane = threadIdx.x & 63, w = threadIdx.x >> 6;
  if (lane == 0) wsum[w] = s;
  __syncthreads();
  if (threadIdx.x == 0) atomicAdd(out, wsum[0] + wsum[1] + wsum[2] + wsum[3]);
}

extern "C" void kernel_launch(void* const* d_in, const int* in_sizes, int n_in,
                              void* d_out, int out_size, void* d_ws, size_t ws_size,
                              hipStream_t stream) {
  const float* gt     = (const float*)d_in[0];
  const float* rec    = (const float*)d_in[1];
  const float* mean   = (const float*)d_in[2];
  const float* logvar = (const float*)d_in[3];
  float* out = (float*)d_out;

  char* ws = (char*)d_ws;
  float4*   gt4   = (float4*)(ws);                  // 32768*16 = 512 KiB
  float4*   rec4  = (float4*)(ws + (512 << 10));    // 512 KiB
  unsigned* d1min = (unsigned*)(ws + (1024 << 10)); // 128 KiB
  unsigned* d2min = (unsigned*)(ws + (1152 << 10)); // 128 KiB

  init_kernel<<<128, 256, 0, stream>>>(gt, rec, gt4, rec4, d1min, d2min, out);
  chamfer_kernel<<<1024, 256, 0, stream>>>(gt4, rec4, d1min, d2min);
  finalize_kernel<<<64, 256, 0, stream>>>(gt4, rec4, d1min, d2min, mean, logvar, out);
}